// Round 6
// baseline (484.132 us; speedup 1.0000x reference)
//
#include <hip/hip_runtime.h>
#include <hip/hip_bf16.h>

#define NB 8
#define CH 256
#define MTOT 16384            // 4*4096 rows
#define ROWSTRIDE 2048        // NB*CH floats per row
#define BM 64
#define KSTEPS 8              // 256/32
#define LDSPITCH 40           // 32 + 8 ushort pad: 2-way bank alias max (free, m136)
#define ABUF 5120             // ushorts per LDS buffer (2 mats * 64 rows * 40)
#define AIOFF 2560            // imag tile offset within buffer (64*40)
#define OFFI 33554432l        // 16384*2048, start of out_i in d_out

typedef __attribute__((ext_vector_type(8))) short bf16x8;
typedef __attribute__((ext_vector_type(4))) float f32x4;

__device__ inline short f2bf(float f) {
    union { float f; unsigned u; } x{f};
    unsigned r = x.u + 0x7fff + ((x.u >> 16) & 1);   // RNE
    return (short)(r >> 16);
}

// ---------------------------------------------------------------------------
// prep: w[mat][b][d][k] f32  ->  wT[mat][b][kc][n][ksub] bf16  (d=kc*32+ksub, n=k)
// ---------------------------------------------------------------------------
__global__ void prep_w(const float* __restrict__ wr, const float* __restrict__ wi,
                       unsigned short* __restrict__ wT) {
    int blk = blockIdx.x;
    int mat = blk >> 8;
    int idx = blk & 255;
    int nc = idx & 3, kc = (idx >> 2) & 7, b = idx >> 5;
    const float* w = mat ? wi : wr;
    __shared__ float tile[32][65];
    int t = threadIdx.x;
    int dd = t >> 3;            // 0..31
    int nn = (t & 7) * 8;       // 0..56
    const float* src = w + (((size_t)b * 256 + kc * 32 + dd) * 256 + nc * 64 + nn);
#pragma unroll
    for (int j = 0; j < 8; ++j) tile[dd][nn + j] = src[j];
    __syncthreads();
    int n = t >> 2;             // 0..63
    int ds = (t & 3) * 8;       // 0,8,16,24
    bf16x8 p;
#pragma unroll
    for (int j = 0; j < 8; ++j) p[j] = f2bf(tile[ds + j][n]);
    unsigned short* dst = wT + (size_t)mat * 524288 + b * 65536 + kc * 8192
                             + (nc * 64 + n) * 32 + ds;
    *(bf16x8*)dst = p;
}

// ---------------------------------------------------------------------------
// complex block GEMM: out_r = Ar*Wr - Ai*Wi + br ; out_i = Ar*Wi + Ai*Wr + bi
// 256 thr = 4 waves, each 64 rows x 64 cols per matrix; block = 64x256 tile.
// 2 blocks/CU (VGPR ~228 -> 2 waves/SIMD): independent barriers per block.
// A: fp32->bf16 inline, LDS dbuf, ONE barrier per K-step.
// W: bf16 frags straight from L2 (1KB/wave coalesced), NAMED even/odd reg bufs
//    (no runtime-indexed register arrays -> no scratch risk, rule #20).
// b = bid&7 == XCD id: W slice L2-resident; A/out disjoint per b.
// ---------------------------------------------------------------------------
__launch_bounds__(256, 2)
__global__ void cgemm(const float* __restrict__ Ar, const float* __restrict__ Ai,
                      const unsigned short* __restrict__ wT,
                      const float* __restrict__ br, const float* __restrict__ bi,
                      float* __restrict__ out) {
    int bid = blockIdx.x;
    int b  = bid & 7;
    int mt = bid >> 3;          // 0..255

    __shared__ unsigned short lds[2 * ABUF];   // 20 KB: [buf][mat][64][40]

    int t = threadIdx.x;
    int lane = t & 63;
    int wc_ = t >> 6;           // 0..3 (wave = 64-col slice)
    int lrow = lane & 15;
    int kseg = lane >> 4;       // 0..3

    // A staging: 256 thr = 64 rows x 4 eight-float segments (full 128B line/row)
    int srow = t >> 2;          // 0..63
    int sseg = t & 3;
    const size_t a_base = (size_t)(mt * BM + srow) * ROWSTRIDE + b * CH + sseg * 8;

    // W fragment base: + mat*524288 + kk*8192 + nf*512
    const unsigned short* wbase = wT + (size_t)b * 65536
                                     + (wc_ * 64 + lrow) * 32 + kseg * 8;

    f32x4 accr[4][4] = {};
    f32x4 acci[4][4] = {};

    f32x4 rR0, rR1, rI0, rI1;                   // A prefetch regs
    bf16x8 wrA[4], wiA[4], wrB[4], wiB[4];      // named W double buffer

#define LOADA(K) { const float* p = Ar + a_base + (size_t)(K) * 32;              \
                   rR0 = *(const f32x4*)p;  rR1 = *(const f32x4*)(p + 4);        \
                   const float* q = Ai + a_base + (size_t)(K) * 32;              \
                   rI0 = *(const f32x4*)q;  rI1 = *(const f32x4*)(q + 4); }
#define LOADW(WR, WI, K) {                                                       \
    const unsigned short* p = wbase + (size_t)(K) * 8192;                        \
    WR[0] = *(const bf16x8*)p;                                                   \
    WR[1] = *(const bf16x8*)(p + 512);                                           \
    WR[2] = *(const bf16x8*)(p + 1024);                                          \
    WR[3] = *(const bf16x8*)(p + 1536);                                          \
    WI[0] = *(const bf16x8*)(p + 524288);                                        \
    WI[1] = *(const bf16x8*)(p + 524800);                                        \
    WI[2] = *(const bf16x8*)(p + 525312);                                        \
    WI[3] = *(const bf16x8*)(p + 525824); }
#define STAGEA(BUF) {                                                            \
    bf16x8 pr, pi;                                                               \
    _Pragma("unroll")                                                            \
    for (int j = 0; j < 4; ++j) { pr[j] = f2bf(rR0[j]); pr[j + 4] = f2bf(rR1[j]);\
                                  pi[j] = f2bf(rI0[j]); pi[j + 4] = f2bf(rI1[j]);}\
    int d0 = (BUF) * ABUF + srow * LDSPITCH + sseg * 8;                          \
    *(bf16x8*)&lds[d0]         = pr;                                             \
    *(bf16x8*)&lds[d0 + AIOFF] = pi; }
#define MFMAS(AB, WR, WI) {                                                      \
    _Pragma("unroll")                                                            \
    for (int mf = 0; mf < 4; ++mf) {                                             \
        int off = (AB) + (mf * 16 + lrow) * LDSPITCH + kseg * 8;                 \
        bf16x8 ar = *(const bf16x8*)&lds[off];                                   \
        bf16x8 ai = *(const bf16x8*)&lds[off + AIOFF];                           \
        bf16x8 ain = ai ^ (short)0x8000;                                         \
        _Pragma("unroll")                                                        \
        for (int nf = 0; nf < 4; ++nf) {                                         \
            accr[mf][nf] = __builtin_amdgcn_mfma_f32_16x16x32_bf16(ar,  WR[nf], accr[mf][nf], 0, 0, 0); \
            accr[mf][nf] = __builtin_amdgcn_mfma_f32_16x16x32_bf16(ain, WI[nf], accr[mf][nf], 0, 0, 0); \
            acci[mf][nf] = __builtin_amdgcn_mfma_f32_16x16x32_bf16(ar,  WI[nf], acci[mf][nf], 0, 0, 0); \
            acci[mf][nf] = __builtin_amdgcn_mfma_f32_16x16x32_bf16(ai,  WR[nf], acci[mf][nf], 0, 0, 0); \
        }                                                                        \
    } }

    // prologue (kk=0 into buf0 / A-regs)
    LOADA(0);
    LOADW(wrA, wiA, 0);
    STAGEA(0);

#pragma unroll
    for (int kt = 0; kt < 4; ++kt) {
        // ---- even step kk = 2kt: reads buf0 + A-bufs; stages buf1 ----
        __syncthreads();
        LOADA(2 * kt + 1);
        LOADW(wrB, wiB, 2 * kt + 1);
        MFMAS(0, wrA, wiA);
        STAGEA(1);
        // ---- odd step kk = 2kt+1: reads buf1 + B-bufs; stages buf0 ----
        __syncthreads();
        if (kt < 3) { LOADA(2 * kt + 2); LOADW(wrA, wiA, 2 * kt + 2); }
        MFMAS(ABUF, wrB, wiB);
        if (kt < 3) STAGEA(0);
    }

    // ---- epilogue: bias + store (C/D: col=lane&15, row=(lane>>4)*4+j, m89/m91) ----
    int colb = wc_ * 64 + lrow;
    int rbase = mt * BM + (lane >> 4) * 4;
#pragma unroll
    for (int nf = 0; nf < 4; ++nf) {
        int col = colb + nf * 16;
        float brv = br[b * CH + col];
        float biv = bi[b * CH + col];
#pragma unroll
        for (int mf = 0; mf < 4; ++mf) {
            size_t ro = (size_t)(rbase + mf * 16) * ROWSTRIDE + b * CH + col;
#pragma unroll
            for (int j = 0; j < 4; ++j) {
                out[ro + (size_t)j * ROWSTRIDE]        = accr[mf][nf][j] + brv;
                out[OFFI + ro + (size_t)j * ROWSTRIDE] = acci[mf][nf][j] + biv;
            }
        }
    }
#undef LOADA
#undef LOADW
#undef STAGEA
#undef MFMAS
}

extern "C" void kernel_launch(void* const* d_in, const int* in_sizes, int n_in,
                              void* d_out, int out_size, void* d_ws, size_t ws_size,
                              hipStream_t stream) {
    const float* real = (const float*)d_in[0];
    const float* imag = (const float*)d_in[1];
    const float* w_r  = (const float*)d_in[2];
    const float* w_i  = (const float*)d_in[3];
    const float* b_r  = (const float*)d_in[4];
    const float* b_i  = (const float*)d_in[5];
    float* out = (float*)d_out;
    unsigned short* wT = (unsigned short*)d_ws;   // 2 MB: [2][8][8][256][32] bf16

    prep_w<<<512, 256, 0, stream>>>(w_r, w_i, wT);
    cgemm<<<(MTOT / BM) * NB, 256, 0, stream>>>(real, imag, wT, b_r, b_i, out);
}